// Round 1
// baseline (853.989 us; speedup 1.0000x reference)
//
#include <hip/hip_runtime.h>
#include <hip/hip_bf16.h>

#define NN 32768
#define NE 524288

__device__ __forceinline__ float silu_f(float x){ return x * (1.0f/(1.0f+__expf(-x))); }
__device__ __forceinline__ float bf2f(unsigned short u){ return __uint_as_float(((unsigned)u)<<16); }
__device__ __forceinline__ unsigned short f2bf(float f){
  unsigned u = __float_as_uint(f);
  u += 0x7fffu + ((u>>16)&1u);   // round-nearest-even
  return (unsigned short)(u>>16);
}

#define S32 0.17677669529663687f   /* 1/sqrt(32) */
#define S8  0.35355339059327373f   /* 1/sqrt(8)  */
#define S64 0.125f                 /* 1/sqrt(64) */
#define R16 0.0625f                /* 1/16       */
#define NSC 0.08838834764831845f   /* 1/sqrt(128)*/
#define INV3F 0.5773502691896258f  /* 1/sqrt(3)  */

// ---------------- CSR build ----------------
__global__ void k_zero(int* __restrict__ deg){
  deg[blockIdx.x*256 + threadIdx.x] = 0;
}

__global__ void k_hist(const int* __restrict__ eidx, int* __restrict__ deg){
  int e = blockIdx.x*256 + threadIdx.x;
  int r = eidx[NE + e];           // receiver row of edge_index (2,E)
  atomicAdd(&deg[r], 1);
}

__global__ void k_scan(const int* __restrict__ deg, int* __restrict__ row_start,
                       int* __restrict__ cursor){
  __shared__ int lds[1024];
  int t = threadIdx.x;
  int base = t*32;
  int local[32];
  int s = 0;
  #pragma unroll
  for (int j=0;j<32;j++){ local[j] = deg[base+j]; s += local[j]; }
  lds[t] = s; __syncthreads();
  for (int off=1; off<1024; off<<=1){
    int v = 0;
    if (t >= off) v = lds[t-off];
    __syncthreads();
    lds[t] += v;
    __syncthreads();
  }
  int run = (t==0) ? 0 : lds[t-1];
  #pragma unroll
  for (int j=0;j<32;j++){
    row_start[base+j] = run; cursor[base+j] = run; run += local[j];
  }
  if (t==1023) row_start[NN] = run;
}

__global__ void k_scatter(const int* __restrict__ eidx, int* __restrict__ cursor,
                          int* __restrict__ csr){
  int e = blockIdx.x*256 + threadIdx.x;
  int r = eidx[NE + e];
  int pos = atomicAdd(&cursor[r], 1);
  csr[pos] = e;
}

// ---------------- node pre-transform: xt = [xs(32) | xv stored i-major (3x32)] ----------------
__global__ void k_xt(const float* __restrict__ nf, const float* __restrict__ W1s,
                     const float* __restrict__ W1v, float* __restrict__ xt){
  int gid = blockIdx.x*256 + threadIdx.x;
  int n = gid >> 7, c = gid & 127;
  const float* row = nf + (size_t)n*128;
  float acc = 0.f;
  if (c < 32){
    #pragma unroll
    for (int u=0;u<32;u++) acc += row[u] * W1s[u*32 + c];
  } else {
    int i = (c-32) >> 5, v = (c-32) & 31;
    #pragma unroll
    for (int u=0;u<32;u++) acc += row[32 + u*3 + i] * W1v[u*32 + v];
  }
  xt[(size_t)n*128 + c] = acc * S32;
}

// ---------------- edge MLP: w[e][128] in bf16 ----------------
__global__ void __launch_bounds__(256) k_mlp(const float* __restrict__ ef,
    const float* __restrict__ Wf1, const float* __restrict__ Wf2,
    const float* __restrict__ Wf3, unsigned short* __restrict__ wout){
  int e = blockIdx.x*256 + threadIdx.x;
  const float4* efv = reinterpret_cast<const float4*>(ef + (size_t)e*8);
  float4 A = efv[0], B = efv[1];
  float xs[8] = {A.x, A.y, A.z, A.w, B.x, B.y, B.z, B.w};

  float h1[64];
  #pragma unroll
  for (int r=0;r<8;r++){
    float xr = xs[r];
    #pragma unroll
    for (int o=0;o<64;o++)
      h1[o] = (r==0) ? xr*Wf1[o] : h1[o] + xr*Wf1[r*64+o];
  }
  #pragma unroll
  for (int o=0;o<64;o++) h1[o] = silu_f(h1[o]*S8);

  float h2[64];
  #pragma unroll
  for (int k=0;k<64;k++){
    float hk = h1[k];
    #pragma unroll
    for (int o=0;o<64;o++)
      h2[o] = (k==0) ? hk*Wf2[o] : h2[o] + hk*Wf2[k*64+o];
  }
  #pragma unroll
  for (int o=0;o<64;o++) h2[o] = silu_f(h2[o]*S64);

  unsigned short* dst = wout + (size_t)e*128;
  #pragma unroll
  for (int half=0; half<2; half++){
    float w[64];
    #pragma unroll
    for (int k=0;k<64;k++){
      float hk = h2[k];
      #pragma unroll
      for (int o=0;o<64;o++)
        w[o] = (k==0) ? hk*Wf3[half*64+o] : w[o] + hk*Wf3[k*128 + half*64 + o];
    }
    #pragma unroll
    for (int g=0; g<8; g++){
      uint4 pk;
      pk.x = ((unsigned)f2bf(w[g*8+1]*S64)<<16) | f2bf(w[g*8+0]*S64);
      pk.y = ((unsigned)f2bf(w[g*8+3]*S64)<<16) | f2bf(w[g*8+2]*S64);
      pk.z = ((unsigned)f2bf(w[g*8+5]*S64)<<16) | f2bf(w[g*8+4]*S64);
      pk.w = ((unsigned)f2bf(w[g*8+7]*S64)<<16) | f2bf(w[g*8+6]*S64);
      reinterpret_cast<uint4*>(dst + half*64)[g] = pk;
    }
  }
}

// ---------------- receiver: gather + aggregate + transforms + gate ----------------
__global__ void __launch_bounds__(256) k_recv(
    const float* __restrict__ nf, const float* __restrict__ na_g,
    const float* __restrict__ ea, const int* __restrict__ eidx,
    const int* __restrict__ row_start, const int* __restrict__ csr,
    const unsigned short* __restrict__ wbuf, const float* __restrict__ xt,
    const float* __restrict__ W2s, const float* __restrict__ W2v,
    const float* __restrict__ Wsc_s, const float* __restrict__ Wsc_v,
    float* __restrict__ out){
  __shared__ float lds[4][320];
  int wv = threadIdx.x >> 6;
  int lane = threadIdx.x & 63;
  int n = blockIdx.x*4 + wv;
  float* L = lds[wv];

  int row = row_start[n], end = row_start[n+1];
  float a0=0.f, a1=0.f, a2=0.f, a3=0.f;
  for (int idx=row; idx<end; ++idx){
    int e   = __builtin_amdgcn_readfirstlane(csr[idx]);
    int snd = __builtin_amdgcn_readfirstlane(eidx[e]);
    float sh0 = ea[(size_t)e*4+0];
    float shx = ea[(size_t)e*4+1];
    float shy = ea[(size_t)e*4+2];
    float shz = ea[(size_t)e*4+3];
    const unsigned short* wr = wbuf + (size_t)e*128;
    const float* xr = xt + (size_t)snd*128;
    if (lane < 32){
      float w0 = bf2f(wr[lane]);
      float w1 = bf2f(wr[32+lane]);
      float xsv = xr[lane];
      a0 += w0*xsv*sh0;
      float t = w1*xsv;
      a1 += t*shx; a2 += t*shy; a3 += t*shz;
    } else {
      int u = lane-32;
      float w2 = bf2f(wr[64+u]);
      float w3 = bf2f(wr[96+u]);
      float xv0 = xr[32+u], xv1 = xr[64+u], xv2 = xr[96+u];
      a0 += w3*(xv0*shx + xv1*shy + xv2*shz)*INV3F;
      float t = w2*sh0;
      a1 += t*xv0; a2 += t*xv1; a3 += t*xv2;
    }
  }
  // agg layout: [s(64) | v_i0(64) | v_i1(64) | v_i2(64)], scaled by 1/AVG_NEIGH
  L[lane]       = a0*R16;
  L[64  + lane] = a1*R16;
  L[128 + lane] = a2*R16;
  L[192 + lane] = a3*R16;
  __syncthreads();

  float na0 = na_g[(size_t)n*4+0], na1 = na_g[(size_t)n*4+1];
  float na2 = na_g[(size_t)n*4+2], na3 = na_g[(size_t)n*4+3];

  // out_s[lane] = agg_s @ W2s /8  + skip_s
  float os = 0.f;
  #pragma unroll 8
  for (int u=0;u<64;u++) os += L[u]*W2s[u*64+lane];
  os *= S64;
  float sk = 0.f;
  #pragma unroll 4
  for (int u=0;u<32;u++){
    float m = na0*Wsc_s[(u*4+0)*64+lane] + na1*Wsc_s[(u*4+1)*64+lane]
            + na2*Wsc_s[(u*4+2)*64+lane] + na3*Wsc_s[(u*4+3)*64+lane];
    sk += nf[(size_t)n*128+u]*m;
  }
  os += sk*NSC;
  float sil = silu_f(os);
  L[256+lane] = sil;   // lanes 32..63 hold gates
  __syncthreads();

  if (lane < 32){
    float ov0=0.f, ov1=0.f, ov2=0.f;
    #pragma unroll 8
    for (int u=0;u<64;u++){
      float w = W2v[u*32+lane];
      ov0 += L[64+u]*w; ov1 += L[128+u]*w; ov2 += L[192+u]*w;
    }
    ov0 *= S64; ov1 *= S64; ov2 *= S64;
    float s0=0.f, s1=0.f, s2=0.f;
    #pragma unroll 4
    for (int u=0;u<32;u++){
      float m = na0*Wsc_v[(u*4+0)*32+lane] + na1*Wsc_v[(u*4+1)*32+lane]
              + na2*Wsc_v[(u*4+2)*32+lane] + na3*Wsc_v[(u*4+3)*32+lane];
      s0 += nf[(size_t)n*128 + 32 + u*3 + 0]*m;
      s1 += nf[(size_t)n*128 + 32 + u*3 + 1]*m;
      s2 += nf[(size_t)n*128 + 32 + u*3 + 2]*m;
    }
    ov0 += s0*NSC; ov1 += s1*NSC; ov2 += s2*NSC;
    float gate = L[256+32+lane];
    size_t b = (size_t)n*128;
    out[b+lane] = nf[b+lane] + sil;
    out[b+32+lane*3+0] = nf[b+32+lane*3+0] + ov0*gate;
    out[b+32+lane*3+1] = nf[b+32+lane*3+1] + ov1*gate;
    out[b+32+lane*3+2] = nf[b+32+lane*3+2] + ov2*gate;
  }
}

extern "C" void kernel_launch(void* const* d_in, const int* in_sizes, int n_in,
                              void* d_out, int out_size, void* d_ws, size_t ws_size,
                              hipStream_t stream) {
  const float* nf    = (const float*)d_in[0];
  const float* na    = (const float*)d_in[1];
  const float* ef    = (const float*)d_in[2];
  const float* ea    = (const float*)d_in[3];
  const float* W1s   = (const float*)d_in[4];
  const float* W1v   = (const float*)d_in[5];
  const float* Wf1   = (const float*)d_in[6];
  const float* Wf2   = (const float*)d_in[7];
  const float* Wf3   = (const float*)d_in[8];
  const float* W2s   = (const float*)d_in[9];
  const float* W2v   = (const float*)d_in[10];
  const float* Wsc_s = (const float*)d_in[11];
  const float* Wsc_v = (const float*)d_in[12];
  const int*   eidx  = (const int*)d_in[13];
  float* out = (float*)d_out;

  char* ws = (char*)d_ws;
  size_t off = 0;
  auto alloc = [&](size_t bytes)->void*{
    void* p = ws + off; off += (bytes + 255) & ~(size_t)255; return p;
  };
  float*          xt        = (float*)alloc((size_t)NN*128*4);
  unsigned short* wbuf      = (unsigned short*)alloc((size_t)NE*128*2);
  int*            deg       = (int*)alloc((size_t)NN*4);
  int*            row_start = (int*)alloc((size_t)(NN+1)*4);
  int*            cursor    = (int*)alloc((size_t)NN*4);
  int*            csr       = (int*)alloc((size_t)NE*4);
  if (off > ws_size) return;  // insufficient scratch — fail visibly

  k_zero   <<<NN/256, 256, 0, stream>>>(deg);
  k_hist   <<<NE/256, 256, 0, stream>>>(eidx, deg);
  k_scan   <<<1, 1024, 0, stream>>>(deg, row_start, cursor);
  k_scatter<<<NE/256, 256, 0, stream>>>(eidx, cursor, csr);
  k_xt     <<<(NN*128)/256, 256, 0, stream>>>(nf, W1s, W1v, xt);
  k_mlp    <<<NE/256, 256, 0, stream>>>(ef, Wf1, Wf2, Wf3, wbuf);
  k_recv   <<<NN/4, 256, 0, stream>>>(nf, na, ea, eidx, row_start, csr,
                                      wbuf, xt, W2s, W2v, Wsc_s, Wsc_v, out);
}

// Round 2
// 401.324 us; speedup vs baseline: 2.1279x; 2.1279x over previous
//
#include <hip/hip_runtime.h>
#include <hip/hip_bf16.h>

#define NN 32768
#define NE 524288

typedef __attribute__((ext_vector_type(8))) short short8v;
typedef __attribute__((ext_vector_type(4))) short short4v;
typedef __attribute__((ext_vector_type(4))) float f32x4;

__device__ __forceinline__ float silu_f(float x){ return x * (1.0f/(1.0f+__expf(-x))); }
__device__ __forceinline__ float bf2f(unsigned short u){ return __uint_as_float(((unsigned)u)<<16); }
__device__ __forceinline__ unsigned short f2bf(float f){
  unsigned u = __float_as_uint(f);
  u += 0x7fffu + ((u>>16)&1u);   // round-nearest-even
  return (unsigned short)(u>>16);
}

#define S32 0.17677669529663687f   /* 1/sqrt(32) */
#define S8  0.35355339059327373f   /* 1/sqrt(8)  */
#define S64 0.125f                 /* 1/sqrt(64) */
#define R16 0.0625f                /* 1/16       */
#define NSC 0.08838834764831845f   /* 1/sqrt(128)*/
#define INV3F 0.5773502691896258f  /* 1/sqrt(3)  */

// ---------------- CSR build ----------------
__global__ void k_zero(int* __restrict__ deg){
  deg[blockIdx.x*256 + threadIdx.x] = 0;
}

__global__ void k_hist(const int* __restrict__ eidx, int* __restrict__ deg){
  int e = blockIdx.x*256 + threadIdx.x;
  int r = eidx[NE + e];           // receiver row of edge_index (2,E)
  atomicAdd(&deg[r], 1);
}

__global__ void k_scan(const int* __restrict__ deg, int* __restrict__ row_start,
                       int* __restrict__ cursor){
  __shared__ int lds[1024];
  int t = threadIdx.x;
  int base = t*32;
  int local[32];
  int s = 0;
  #pragma unroll
  for (int j=0;j<32;j++){ local[j] = deg[base+j]; s += local[j]; }
  lds[t] = s; __syncthreads();
  for (int off=1; off<1024; off<<=1){
    int v = 0;
    if (t >= off) v = lds[t-off];
    __syncthreads();
    lds[t] += v;
    __syncthreads();
  }
  int run = (t==0) ? 0 : lds[t-1];
  #pragma unroll
  for (int j=0;j<32;j++){
    row_start[base+j] = run; cursor[base+j] = run; run += local[j];
  }
  if (t==1023) row_start[NN] = run;
}

__global__ void k_scatter(const int* __restrict__ eidx, int* __restrict__ cursor,
                          int* __restrict__ csr){
  int e = blockIdx.x*256 + threadIdx.x;
  int r = eidx[NE + e];
  int pos = atomicAdd(&cursor[r], 1);
  csr[pos] = e;
}

// ---------------- node pre-transform: xt = [xs(32) | xv stored i-major (3x32)] ----------------
__global__ void k_xt(const float* __restrict__ nf, const float* __restrict__ W1s,
                     const float* __restrict__ W1v, float* __restrict__ xt){
  int gid = blockIdx.x*256 + threadIdx.x;
  int n = gid >> 7, c = gid & 127;
  const float* row = nf + (size_t)n*128;
  float acc = 0.f;
  if (c < 32){
    #pragma unroll
    for (int u=0;u<32;u++) acc += row[u] * W1s[u*32 + c];
  } else {
    int i = (c-32) >> 5, v = (c-32) & 31;
    #pragma unroll
    for (int u=0;u<32;u++) acc += row[32 + u*3 + i] * W1v[u*32 + v];
  }
  xt[(size_t)n*128 + c] = acc * S32;
}

// ---------------- weight fragment prep for MFMA MLP ----------------
// frag f, lane l: A-operand fragment of W^T tile (m, kk).
// element j <-> k_in_block = 16*(j>=4) + (l>>4)*4 + (j&3)
// f in [0,4):  layer1, m=f,        val = (k<8) ? Wf1[k*64  + m*16 + c] : 0
// f in [4,12): layer2, m=(f-4)>>1, kk=(f-4)&1: val = Wf2[(kk*32+k)*64  + m*16 + c]
// f in [12,28):layer3, m=(f-12)>>1,kk=(f-12)&1: val = Wf3[(kk*32+k)*128 + m*16 + c]
__global__ void k_wprep(const float* __restrict__ Wf1, const float* __restrict__ Wf2,
                        const float* __restrict__ Wf3, short* __restrict__ wfrag){
  int f = blockIdx.x;
  int l = threadIdx.x;
  int c = l & 15, g = l >> 4;
  short v[8];
  #pragma unroll
  for (int j=0;j<8;j++){
    int k = ((j&4) ? 16 : 0) + g*4 + (j&3);
    float val;
    if (f < 4){
      int m = f;
      val = (k < 8) ? Wf1[k*64 + m*16 + c] : 0.f;
    } else if (f < 12){
      int idx = f-4, m = idx>>1, kk = idx&1;
      val = Wf2[(kk*32+k)*64 + m*16 + c];
    } else {
      int idx = f-12, m = idx>>1, kk = idx&1;
      val = Wf3[(kk*32+k)*128 + m*16 + c];
    }
    v[j] = (short)f2bf(val);
  }
  short8v pk;
  #pragma unroll
  for (int j=0;j<8;j++) pk[j] = v[j];
  reinterpret_cast<short8v*>(wfrag)[f*64 + l] = pk;
}

// ---------------- edge MLP via MFMA: w[e][128] in bf16 ----------------
// Transposed compute: h^T = W^T . x^T ; M=out_dim, N=16 edges, K=in_dim.
// D layout: row(out) = (l>>4)*4+reg, col(edge) = l&15.
// LDS h layout: chunked [k/4][edge][4] bf16 (8B units) per wave.
__global__ void __launch_bounds__(256,2) k_mlp2(const float* __restrict__ ef,
    const short* __restrict__ wfrag, unsigned short* __restrict__ wout){
  __shared__ short hbuf[4][2][1024];
  int lane = threadIdx.x & 63;
  int wv = threadIdx.x >> 6;
  int wid = blockIdx.x*4 + wv;
  int e_l = lane & 15, g = lane >> 4;

  short8v F[28];
  const short8v* wf = reinterpret_cast<const short8v*>(wfrag);
  #pragma unroll
  for (int f=0; f<28; f++) F[f] = wf[f*64 + lane];

  short* h1 = &hbuf[wv][0][0];
  short* h2 = &hbuf[wv][1][0];

  #pragma unroll 1
  for (int s=0; s<8; s++){
    int tile = wid + s*4096;
    // ---- layer 1: B frag from edge_feats (K=8 padded to 32) ----
    short8v bx = {};
    if (lane < 32){
      const float4 xv = *reinterpret_cast<const float4*>(
          ef + (size_t)(tile*16 + e_l)*8 + g*4);
      bx[0]=(short)f2bf(xv.x); bx[1]=(short)f2bf(xv.y);
      bx[2]=(short)f2bf(xv.z); bx[3]=(short)f2bf(xv.w);
    }
    #pragma unroll
    for (int m=0;m<4;m++){
      f32x4 acc = {};
      acc = __builtin_amdgcn_mfma_f32_16x16x32_bf16(F[m], bx, acc, 0,0,0);
      short4v pk;
      #pragma unroll
      for (int r=0;r<4;r++) pk[r] = (short)f2bf(silu_f(acc[r]*S8));
      *reinterpret_cast<short4v*>(&h1[((4*m+g)*16 + e_l)*4]) = pk;
    }
    // ---- layer 2: K=64 ----
    f32x4 acc2[4] = {};
    #pragma unroll
    for (int kk=0;kk<2;kk++){
      short4v r0 = *reinterpret_cast<short4v*>(&h1[((kk*8+g  )*16 + e_l)*4]);
      short4v r1 = *reinterpret_cast<short4v*>(&h1[((kk*8+4+g)*16 + e_l)*4]);
      short8v b;
      b[0]=r0[0]; b[1]=r0[1]; b[2]=r0[2]; b[3]=r0[3];
      b[4]=r1[0]; b[5]=r1[1]; b[6]=r1[2]; b[7]=r1[3];
      #pragma unroll
      for (int m=0;m<4;m++)
        acc2[m] = __builtin_amdgcn_mfma_f32_16x16x32_bf16(F[4+2*m+kk], b, acc2[m], 0,0,0);
    }
    #pragma unroll
    for (int m=0;m<4;m++){
      short4v pk;
      #pragma unroll
      for (int r=0;r<4;r++) pk[r] = (short)f2bf(silu_f(acc2[m][r]*S64));
      *reinterpret_cast<short4v*>(&h2[((4*m+g)*16 + e_l)*4]) = pk;
    }
    // ---- layer 3: K=64, 128 outputs ----
    f32x4 acc3[8] = {};
    #pragma unroll
    for (int kk=0;kk<2;kk++){
      short4v r0 = *reinterpret_cast<short4v*>(&h2[((kk*8+g  )*16 + e_l)*4]);
      short4v r1 = *reinterpret_cast<short4v*>(&h2[((kk*8+4+g)*16 + e_l)*4]);
      short8v b;
      b[0]=r0[0]; b[1]=r0[1]; b[2]=r0[2]; b[3]=r0[3];
      b[4]=r1[0]; b[5]=r1[1]; b[6]=r1[2]; b[7]=r1[3];
      #pragma unroll
      for (int m=0;m<8;m++)
        acc3[m] = __builtin_amdgcn_mfma_f32_16x16x32_bf16(F[12+2*m+kk], b, acc3[m], 0,0,0);
    }
    // ---- store w (scaled by S64) ----
    unsigned short* dst = wout + (size_t)(tile*16 + e_l)*128;
    #pragma unroll
    for (int m=0;m<8;m++){
      uint2 pk;
      unsigned v0 = f2bf(acc3[m][0]*S64), v1 = f2bf(acc3[m][1]*S64);
      unsigned v2 = f2bf(acc3[m][2]*S64), v3 = f2bf(acc3[m][3]*S64);
      pk.x = v0 | (v1<<16);
      pk.y = v2 | (v3<<16);
      *reinterpret_cast<uint2*>(dst + m*16 + g*4) = pk;
    }
  }
}

// ---------------- receiver: gather + aggregate + transforms + gate ----------------
__global__ void __launch_bounds__(256) k_recv(
    const float* __restrict__ nf, const float* __restrict__ na_g,
    const float* __restrict__ ea, const int* __restrict__ eidx,
    const int* __restrict__ row_start, const int* __restrict__ csr,
    const unsigned short* __restrict__ wbuf, const float* __restrict__ xt,
    const float* __restrict__ W2s, const float* __restrict__ W2v,
    const float* __restrict__ Wsc_s, const float* __restrict__ Wsc_v,
    float* __restrict__ out){
  __shared__ float lds[4][320];
  int wv = threadIdx.x >> 6;
  int lane = threadIdx.x & 63;
  int n = blockIdx.x*4 + wv;
  float* L = lds[wv];

  int row = row_start[n], end = row_start[n+1];
  float a0=0.f, a1=0.f, a2=0.f, a3=0.f;
  for (int idx=row; idx<end; ++idx){
    int e   = __builtin_amdgcn_readfirstlane(csr[idx]);
    int snd = __builtin_amdgcn_readfirstlane(eidx[e]);
    float sh0 = ea[(size_t)e*4+0];
    float shx = ea[(size_t)e*4+1];
    float shy = ea[(size_t)e*4+2];
    float shz = ea[(size_t)e*4+3];
    const unsigned short* wr = wbuf + (size_t)e*128;
    const float* xr = xt + (size_t)snd*128;
    if (lane < 32){
      float w0 = bf2f(wr[lane]);
      float w1 = bf2f(wr[32+lane]);
      float xsv = xr[lane];
      a0 += w0*xsv*sh0;
      float t = w1*xsv;
      a1 += t*shx; a2 += t*shy; a3 += t*shz;
    } else {
      int u = lane-32;
      float w2 = bf2f(wr[64+u]);
      float w3 = bf2f(wr[96+u]);
      float xv0 = xr[32+u], xv1 = xr[64+u], xv2 = xr[96+u];
      a0 += w3*(xv0*shx + xv1*shy + xv2*shz)*INV3F;
      float t = w2*sh0;
      a1 += t*xv0; a2 += t*xv1; a3 += t*xv2;
    }
  }
  // agg layout: [s(64) | v_i0(64) | v_i1(64) | v_i2(64)], scaled by 1/AVG_NEIGH
  L[lane]       = a0*R16;
  L[64  + lane] = a1*R16;
  L[128 + lane] = a2*R16;
  L[192 + lane] = a3*R16;
  __syncthreads();

  float na0 = na_g[(size_t)n*4+0], na1 = na_g[(size_t)n*4+1];
  float na2 = na_g[(size_t)n*4+2], na3 = na_g[(size_t)n*4+3];

  // out_s[lane] = agg_s @ W2s /8  + skip_s
  float os = 0.f;
  #pragma unroll 8
  for (int u=0;u<64;u++) os += L[u]*W2s[u*64+lane];
  os *= S64;
  float sk = 0.f;
  #pragma unroll 4
  for (int u=0;u<32;u++){
    float m = na0*Wsc_s[(u*4+0)*64+lane] + na1*Wsc_s[(u*4+1)*64+lane]
            + na2*Wsc_s[(u*4+2)*64+lane] + na3*Wsc_s[(u*4+3)*64+lane];
    sk += nf[(size_t)n*128+u]*m;
  }
  os += sk*NSC;
  float sil = silu_f(os);
  L[256+lane] = sil;   // lanes 32..63 hold gates
  __syncthreads();

  if (lane < 32){
    float ov0=0.f, ov1=0.f, ov2=0.f;
    #pragma unroll 8
    for (int u=0;u<64;u++){
      float w = W2v[u*32+lane];
      ov0 += L[64+u]*w; ov1 += L[128+u]*w; ov2 += L[192+u]*w;
    }
    ov0 *= S64; ov1 *= S64; ov2 *= S64;
    float s0=0.f, s1=0.f, s2=0.f;
    #pragma unroll 4
    for (int u=0;u<32;u++){
      float m = na0*Wsc_v[(u*4+0)*32+lane] + na1*Wsc_v[(u*4+1)*32+lane]
              + na2*Wsc_v[(u*4+2)*32+lane] + na3*Wsc_v[(u*4+3)*32+lane];
      s0 += nf[(size_t)n*128 + 32 + u*3 + 0]*m;
      s1 += nf[(size_t)n*128 + 32 + u*3 + 1]*m;
      s2 += nf[(size_t)n*128 + 32 + u*3 + 2]*m;
    }
    ov0 += s0*NSC; ov1 += s1*NSC; ov2 += s2*NSC;
    float gate = L[256+32+lane];
    size_t b = (size_t)n*128;
    out[b+lane] = nf[b+lane] + sil;
    out[b+32+lane*3+0] = nf[b+32+lane*3+0] + ov0*gate;
    out[b+32+lane*3+1] = nf[b+32+lane*3+1] + ov1*gate;
    out[b+32+lane*3+2] = nf[b+32+lane*3+2] + ov2*gate;
  }
}

extern "C" void kernel_launch(void* const* d_in, const int* in_sizes, int n_in,
                              void* d_out, int out_size, void* d_ws, size_t ws_size,
                              hipStream_t stream) {
  const float* nf    = (const float*)d_in[0];
  const float* na    = (const float*)d_in[1];
  const float* ef    = (const float*)d_in[2];
  const float* ea    = (const float*)d_in[3];
  const float* W1s   = (const float*)d_in[4];
  const float* W1v   = (const float*)d_in[5];
  const float* Wf1   = (const float*)d_in[6];
  const float* Wf2   = (const float*)d_in[7];
  const float* Wf3   = (const float*)d_in[8];
  const float* W2s   = (const float*)d_in[9];
  const float* W2v   = (const float*)d_in[10];
  const float* Wsc_s = (const float*)d_in[11];
  const float* Wsc_v = (const float*)d_in[12];
  const int*   eidx  = (const int*)d_in[13];
  float* out = (float*)d_out;

  char* ws = (char*)d_ws;
  size_t off = 0;
  auto alloc = [&](size_t bytes)->void*{
    void* p = ws + off; off += (bytes + 255) & ~(size_t)255; return p;
  };
  float*          xt        = (float*)alloc((size_t)NN*128*4);
  unsigned short* wbuf      = (unsigned short*)alloc((size_t)NE*128*2);
  int*            deg       = (int*)alloc((size_t)NN*4);
  int*            row_start = (int*)alloc((size_t)(NN+1)*4);
  int*            cursor    = (int*)alloc((size_t)NN*4);
  int*            csr       = (int*)alloc((size_t)NE*4);
  short*          wfrag     = (short*)alloc((size_t)28*64*8*2);
  if (off > ws_size) return;  // insufficient scratch — fail visibly

  k_zero   <<<NN/256, 256, 0, stream>>>(deg);
  k_hist   <<<NE/256, 256, 0, stream>>>(eidx, deg);
  k_scan   <<<1, 1024, 0, stream>>>(deg, row_start, cursor);
  k_scatter<<<NE/256, 256, 0, stream>>>(eidx, cursor, csr);
  k_xt     <<<(NN*128)/256, 256, 0, stream>>>(nf, W1s, W1v, xt);
  k_wprep  <<<28, 64, 0, stream>>>(Wf1, Wf2, Wf3, wfrag);
  k_mlp2   <<<1024, 256, 0, stream>>>(ef, wfrag, wbuf);
  k_recv   <<<NN/4, 256, 0, stream>>>(nf, na, ea, eidx, row_start, csr,
                                      wbuf, xt, W2s, W2v, Wsc_s, Wsc_v, out);
}